// Round 17
// baseline (779.375 us; speedup 1.0000x reference)
//
#include <hip/hip_runtime.h>

#define B_ 8
#define N_ 8192
#define H_ 8
#define KSPLIT 16
#define BN 65536  // B_*N_

typedef float f32x4 __attribute__((ext_vector_type(4)));
typedef __bf16 bf16x8 __attribute__((ext_vector_type(8)));
typedef unsigned short u16;

__device__ __forceinline__ u16 f2b(float f) {
  union { float f; unsigned u; } v; v.f = f;
  return (u16)((v.u + 0x7fffu + ((v.u >> 16) & 1u)) >> 16);
}
__device__ __forceinline__ float b2f(u16 u) {
  union { unsigned u; float f; } v; v.u = ((unsigned)u) << 16;
  return v.f;
}

// async global->LDS 16B
__device__ __forceinline__ void gload16(const void* g, const void* lds) {
  __builtin_amdgcn_global_load_lds(
      (const __attribute__((address_space(1))) unsigned int*)(unsigned long long)g,
      (__attribute__((address_space(3))) unsigned int*)(unsigned long long)lds,
      16, 0, 0);
}

__device__ __forceinline__ void ld16f(const float* p, float* f) {
#pragma unroll
  for (int j = 0; j < 4; ++j) {
    float4 q = *(const float4*)(p + j * 4);
    f[j * 4 + 0] = q.x; f[j * 4 + 1] = q.y; f[j * 4 + 2] = q.z; f[j * 4 + 3] = q.w;
  }
}
__device__ __forceinline__ void ld16b(const u16* p, float* f) {
  uint4 a = *(const uint4*)p, b = *(const uint4*)(p + 8);
  const unsigned uu[8] = {a.x, a.y, a.z, a.w, b.x, b.y, b.z, b.w};
#pragma unroll
  for (int j = 0; j < 8; ++j) {
    f[2 * j]     = b2f((u16)(uu[j] & 0xffff));
    f[2 * j + 1] = b2f((u16)(uu[j] >> 16));
  }
}
__device__ __forceinline__ void st16b(u16* p, const float* f) {
  u16 o[16];
#pragma unroll
  for (int j = 0; j < 16; ++j) o[j] = f2b(f[j]);
  *(uint4*)p = *(const uint4*)o;
  *(uint4*)(p + 8) = *(const uint4*)(o + 8);
}
__device__ __forceinline__ void st16f(float* p, const float* f) {
#pragma unroll
  for (int j = 0; j < 4; ++j) {
    float4 q; q.x = f[j * 4]; q.y = f[j * 4 + 1]; q.z = f[j * 4 + 2]; q.w = f[j * 4 + 3];
    *(float4*)(p + j * 4) = q;
  }
}

// ---------------------------------------------------------------------------
// 8-phase bf16 MFMA GEMM (m201-style), 256x256 tile, 512 threads (8 waves =
// 2M x 4N of 128x64), BK=64 split in 2 k-halves. Half-tile H = {A,B} x khalf
// (4 loads/thread). Phase (kh, mh): 8 ds_read_b128 + stage half H+2 part ->
// barrier -> lgkmcnt(0) -> setprio(1) 16 MFMA setprio(0) -> [vmcnt(4|0) at
// half boundary] barrier. Loads never drain mid-loop (vmcnt(4) steady).
// LDS 128 KB (As[2][2] + Bs[2][2] k-half slices); epilogue scr over As after
// full drain. MODEs identical to round 16.
// ---------------------------------------------------------------------------
template <int MODE, int XBF, int CF32, int BSEL>
__global__ __launch_bounds__(512) void gemm2(
    const u16* __restrict__ A1, int lda1, const u16* __restrict__ A2, int lda2,
    const u16* __restrict__ BT, int ldb,
    const float* __restrict__ bias, const void* __restrict__ auxX,
    const u16* __restrict__ auxZ, const float* __restrict__ auxS,
    void* __restrict__ Cv, void* __restrict__ Cv2, void* __restrict__ Cv3,
    int ldc, int K) {
  __shared__ __align__(16) u16 As[2][2][8192];  // [dbuf][khalf][256r x 32k]
  __shared__ __align__(16) u16 Bs[2][2][8192];
  const int t = threadIdx.x, lane = t & 63, w = t >> 6;  // w in 0..7
  const int nwg = gridDim.x * gridDim.y;
  const int flat = blockIdx.x + gridDim.x * blockIdx.y;
  const int wg = (flat & 7) * (nwg >> 3) + (flat >> 3);  // XCD-aware remap
  const int bx = wg % gridDim.x, by = wg / gridDim.x;
  const int rowBase = by * 256, colBase = bx * 256;
  const int aBase = (BSEL == 2) ? 0 : rowBase;  // BSEL2: A rows wrap mod 256
  const u16* BTb = BT;
  if (BSEL == 1) BTb = BT + (size_t)(rowBase >> 13) * 131072;
  if (BSEL == 2) BTb = BT + (size_t)(rowBase >> 8) * 131072;

  const int lr = lane & 15, kg = lane >> 4;
  const int wrow = (w >> 2) * 128, wcol = (w & 3) * 64;

  f32x4 acc[8][4];
#pragma unroll
  for (int m = 0; m < 8; ++m)
#pragma unroll
    for (int n = 0; n < 4; ++n) acc[m][n] = 0.f;

  const int NT = K >> 6;        // K-tiles of 64
  const int NH = NT * 2;        // half-tiles (k-half granules)

  auto stageA = [&](int H) {    // A part of half H: 2 gload16
    const int tile = H >> 1, kh = H & 1, buf = tile & 1;
    const int k0 = tile * 64 + kh * 32;
    const u16* Ap; int la, ka;
    if (k0 < 256) { Ap = A1; la = lda1; ka = k0; }
    else          { Ap = A2; la = lda2; ka = k0 - 256; }
#pragma unroll
    for (int j = 0; j < 2; ++j) {
      int g = j * 512 + t;
      int row = g >> 2, sl = g & 3;
      gload16(&Ap[(size_t)(aBase + row) * la + ka + (sl ^ ((row & 6) >> 1)) * 8],
              &As[buf][kh][g * 8]);
    }
  };
  auto stageB = [&](int H) {    // B part of half H: 2 gload16
    const int tile = H >> 1, kh = H & 1, buf = tile & 1;
    const int k0 = tile * 64 + kh * 32;
#pragma unroll
    for (int j = 0; j < 2; ++j) {
      int g = j * 512 + t;
      int col = g >> 2, sl = g & 3;
      gload16(&BTb[(size_t)(colBase + col) * ldb + k0 + (sl ^ ((col & 6) >> 1)) * 8],
              &Bs[buf][kh][g * 8]);
    }
  };

  auto sbar = [&]() {
    __builtin_amdgcn_sched_barrier(0);
    __builtin_amdgcn_s_barrier();
    __builtin_amdgcn_sched_barrier(0);
  };

  // prologue: halves 0,1 fully staged (8 loads); confirm half 0 globally.
  stageA(0); stageB(0);
  stageA(1); stageB(1);
  asm volatile("s_waitcnt vmcnt(4)" ::: "memory");
  sbar();

  for (int h = 0; h < NH; ++h) {
    const int tile = h >> 1, kh = h & 1, buf = tile & 1;
#pragma unroll
    for (int mh = 0; mh < 2; ++mh) {
      // ds_read this phase's fragments
      bf16x8 af[4], bf[4];
#pragma unroll
      for (int i = 0; i < 4; ++i) {
        int r = wrow + mh * 64 + i * 16 + lr;
        af[i] = *(const bf16x8*)&As[buf][kh][r * 32 + (kg ^ ((r & 6) >> 1)) * 8];
      }
#pragma unroll
      for (int n = 0; n < 4; ++n) {
        int c = wcol + n * 16 + lr;
        bf[n] = *(const bf16x8*)&Bs[buf][kh][c * 32 + (kg ^ ((c & 6) >> 1)) * 8];
      }
      // stage half h+2 (A-part on phase 0, B-part on phase 1)
      if (h + 2 < NH) {
        if (mh == 0) stageA(h + 2);
        else         stageB(h + 2);
      }
      sbar();                                  // frag reads + stages ordered
      asm volatile("s_waitcnt lgkmcnt(0)" ::: "memory");
      __builtin_amdgcn_sched_barrier(0);
      __builtin_amdgcn_s_setprio(1);
#pragma unroll
      for (int m = 0; m < 4; ++m)
#pragma unroll
        for (int n = 0; n < 4; ++n)
          acc[mh * 4 + m][n] =
              __builtin_amdgcn_mfma_f32_16x16x32_bf16(af[m], bf[n], acc[mh * 4 + m][n], 0, 0, 0);
      __builtin_amdgcn_s_setprio(0);
      // at half boundary, confirm next half landed (never drain mid-loop)
      if (mh == 1 && h + 1 < NH) {
        if (h + 2 < NH) asm volatile("s_waitcnt vmcnt(4)" ::: "memory");
        else            asm volatile("s_waitcnt vmcnt(0)" ::: "memory");
      }
      sbar();
    }
  }

  // ---- epilogue: repack via scr (aliased over As; vmem fully drained) ----
  asm volatile("s_waitcnt vmcnt(0) lgkmcnt(0)" ::: "memory");
  sbar();
  float* scr = (float*)&As[0][0][0];  // 32 x 260 f32 = 33.3 KB (As = 64 KB)
#pragma unroll
  for (int mf = 0; mf < 8; ++mf) {
    if (mf) {
      asm volatile("s_waitcnt lgkmcnt(0)" ::: "memory");
      sbar();
    }
#pragma unroll
    for (int n = 0; n < 4; ++n)
#pragma unroll
      for (int i = 0; i < 4; ++i)
        scr[((w >> 2) * 16 + kg * 4 + i) * 260 + wcol + n * 16 + lr] = acc[mf][n][i];
    asm volatile("s_waitcnt lgkmcnt(0)" ::: "memory");
    sbar();
    const int sr = t >> 4, cs = (t & 15) * 16;
    const int grow = rowBase + (sr >> 4) * 128 + mf * 16 + (sr & 15);
    const int gcol = colBase + cs;
    float vv[16];
#pragma unroll
    for (int j = 0; j < 4; ++j) {
      float4 q = *(const float4*)&scr[sr * 260 + cs + j * 4];
      vv[j * 4] = q.x; vv[j * 4 + 1] = q.y; vv[j * 4 + 2] = q.z; vv[j * 4 + 3] = q.w;
    }
    if (MODE == 0 || MODE == 1) {
      float bb[16]; ld16f(&bias[gcol], bb);
#pragma unroll
      for (int j = 0; j < 16; ++j) {
        vv[j] += bb[j];
        if (MODE == 1) vv[j] = fmaxf(vv[j], 0.f);
      }
      st16b(&((u16*)Cv)[(size_t)grow * ldc + gcol], vv);
    } else if (MODE == 10) {
      float bb[16]; ld16f(&bias[gcol], bb);
      float sx = auxS[(size_t)grow * 8 + (gcol >> 6)];
#pragma unroll
      for (int j = 0; j < 16; ++j) vv[j] = __expf(vv[j] + bb[j] - sx) * 0.125f;
      const float* kvf = (const float*)auxX;  // kvfin
      float sv[16];
      ld16f(&kvf[((size_t)(grow >> 13) * 8 + (gcol >> 6)) * 2112 + 2048 + (gcol & 63)], sv);
      float dp = 0.f;
#pragma unroll
      for (int j = 0; j < 16; ++j) dp = __fmaf_rn(vv[j], sv[j], dp);
      dp += __shfl_xor(dp, 1);
      dp += __shfl_xor(dp, 2);
      const float r = 1.0f / dp;
#pragma unroll
      for (int j = 0; j < 16; ++j) vv[j] *= r;
      st16b(&((u16*)Cv)[(size_t)grow * ldc + gcol], vv);
    } else if (MODE == 7) {
      float bb[16]; ld16f(&bias[gcol], bb);
#pragma unroll
      for (int j = 0; j < 16; ++j) vv[j] += bb[j];
      if (colBase < 512) {
        u16* Cp; int c2;
        if (colBase < 256) { Cp = (u16*)Cv;  c2 = gcol; }
        else               { Cp = (u16*)Cv2; c2 = gcol - 256; }
        st16b(&Cp[(size_t)grow * ldc + c2], vv);
      } else {  // Q: sq only, no store
        float s = 0.f;
#pragma unroll
        for (int j = 0; j < 16; ++j) s += vv[j] * vv[j];
        s += __shfl_xor(s, 1);
        if ((t & 1) == 0)
          const_cast<float*>(auxS)[(size_t)grow * 8 + ((gcol - 512) >> 5)] =
              0.0883883476483184f * s;
      }
    } else if (MODE == 8) {
      if (colBase < 256) {
        float xv[16];
        if (XBF) ld16b(&((const u16*)auxX)[(size_t)grow * 256 + gcol], xv);
        else     ld16f(&((const float*)auxX)[(size_t)grow * 256 + gcol], xv);
#pragma unroll
        for (int j = 0; j < 16; ++j) vv[j] = (1.f / (1.f + __expf(-vv[j]))) * xv[j];
        st16b(&((u16*)Cv)[(size_t)grow * ldc + gcol], vv);
      } else {
        float bb[16]; ld16f(&bias[gcol - 256], bb);
#pragma unroll
        for (int j = 0; j < 16; ++j) vv[j] = 1.f / (1.f + __expf(-(vv[j] - bb[j])));
        st16b(&((u16*)Cv2)[(size_t)grow * ldc + gcol - 256], vv);
      }
    } else if (MODE == 4) {
      float zz[16], xv[16];
      ld16b(&auxZ[(size_t)grow * 256 + gcol], zz);
      if (XBF) ld16b(&((const u16*)auxX)[(size_t)grow * 256 + gcol], xv);
      else     ld16f(&((const float*)auxX)[(size_t)grow * 256 + gcol], xv);
#pragma unroll
      for (int j = 0; j < 16; ++j)
        vv[j] = (1.f - zz[j]) * xv[j] + zz[j] * tanhf(vv[j]);
      if (CF32) st16f(&((float*)Cv)[(size_t)grow * ldc + gcol], vv);
      else      st16b(&((u16*)Cv)[(size_t)grow * ldc + gcol], vv);
    } else if (MODE == 9) {
      float zz[16], xv[16];
      ld16b(&auxZ[(size_t)grow * 256 + gcol], zz);
      ld16b(&((const u16*)auxX)[(size_t)grow * 256 + gcol], xv);
#pragma unroll
      for (int j = 0; j < 16; ++j)
        vv[j] = (1.f - zz[j]) * xv[j] + zz[j] * tanhf(vv[j]);
      st16b(&((u16*)Cv)[(size_t)grow * 256 + gcol], vv);
      float s1 = 0.f, s2 = 0.f;
#pragma unroll
      for (int j = 0; j < 16; ++j) { s1 += vv[j]; s2 += vv[j] * vv[j]; }
#pragma unroll
      for (int off = 1; off < 16; off <<= 1) {
        s1 += __shfl_xor(s1, off);
        s2 += __shfl_xor(s2, off);
      }
      float mu = s1 * (1.f / 256.f);
      float var = s2 * (1.f / 256.f) - mu * mu;
      float rs = rsqrtf(var + 1e-3f);
      float gg[16], bb2[16];
      ld16f(&bias[gcol], gg);
      ld16f(&auxS[gcol], bb2);
#pragma unroll
      for (int j = 0; j < 16; ++j) vv[j] = gg[j] * (vv[j] - mu) * rs + bb2[j];
      st16b(&((u16*)Cv2)[(size_t)grow * 256 + gcol], vv);
    }
  }
}

// ---------------------------------------------------------------------------
// Fused phi_k + sq + kv kernel (unchanged, proven).
// ---------------------------------------------------------------------------
__global__ __launch_bounds__(256) void fkv_kernel(const u16* __restrict__ Kb,
                                                  const u16* __restrict__ Vb,
                                                  const u16* __restrict__ omT,
                                                  float* __restrict__ part) {
  __shared__ __align__(16) char smem[33792];
  u16* Ks  = (u16*)smem;
  u16* omS = Ks + 4096;
  u16* pkT = omS + 2048;
  u16* vT  = pkT + 64 * 72;
  float* sqL = (float*)(vT + 48 * 72);
  float* red = (float*)smem;

  const int bh = blockIdx.x, split = blockIdx.y;
  const int b = bh >> 3, h = bh & 7;
  const int t = threadIdx.x, lane = t & 63, w = t >> 6;
  const int lr = lane & 15, kg = lane >> 4;
  const size_t rbase = (size_t)b * N_ + (size_t)split * (N_ / KSPLIT);

  {
    int m = t >> 2, sl = t & 3;
    gload16(&omT[m * 32 + ((sl ^ ((m & 6) >> 1)) * 8)], &omS[t * 8]);
  }
  for (int i = t; i < 16 * 128; i += 256) {
    int r = 32 + (i >> 7), tok = i & 127;
    vT[r * 72 + tok] = (r == 32) ? (u16)0x3f80 : (u16)0;
  }

  f32x4 kacc[4][3];
#pragma unroll
  for (int mi = 0; mi < 4; ++mi)
#pragma unroll
    for (int ni = 0; ni < 3; ++ni) kacc[mi][ni] = 0.f;

  for (int tile = 0; tile < (N_ / KSPLIT) / 128; ++tile) {
    __syncthreads();
    const size_t gt0 = rbase + tile * 128;
#pragma unroll
    for (int j = 0; j < 2; ++j) {
      int slot = j * 256 + t;
      int tok = slot >> 2, sl = slot & 3;
      gload16(&Kb[(gt0 + tok) * 256 + h * 32 + ((sl ^ ((tok & 6) >> 1)) * 8)],
              &Ks[slot * 8]);
    }
#pragma unroll
    for (int j = 0; j < 2; ++j) {
      int slot = j * 256 + t;
      int tok = slot >> 2, seg = slot & 3;
      uint4 q = *(const uint4*)&Vb[(gt0 + tok) * 256 + h * 32 + seg * 8];
      const unsigned uu[4] = {q.x, q.y, q.z, q.w};
#pragma unroll
      for (int jj = 0; jj < 4; ++jj) {
        vT[(seg * 8 + jj * 2 + 0) * 72 + tok] = (u16)(uu[jj] & 0xffffu);
        vT[(seg * 8 + jj * 2 + 1) * 72 + tok] = (u16)(uu[jj] >> 16);
      }
    }
    asm volatile("s_waitcnt vmcnt(0)" ::: "memory");
    __syncthreads();

    uint4 araw[2];
    bf16x8 af[2];
#pragma unroll
    for (int mi = 0; mi < 2; ++mi) {
      int row = w * 32 + mi * 16 + lr;
      araw[mi] = *(const uint4*)&Ks[row * 32 + (kg ^ ((row & 6) >> 1)) * 8];
      af[mi] = *(const bf16x8*)&araw[mi];
    }
#pragma unroll
    for (int mi = 0; mi < 2; ++mi) {
      const unsigned uu[4] = {araw[mi].x, araw[mi].y, araw[mi].z, araw[mi].w};
      float s = 0.f;
#pragma unroll
      for (int j = 0; j < 4; ++j) {
        float lo = b2f((u16)(uu[j] & 0xffffu)), hi = b2f((u16)(uu[j] >> 16));
        s = __fmaf_rn(lo, lo, s); s = __fmaf_rn(hi, hi, s);
      }
      s += __shfl_xor(s, 16);
      s += __shfl_xor(s, 32);
      if (lane < 16) sqL[w * 32 + mi * 16 + lr] = 0.0883883476483184f * s;
    }
    bf16x8 bo[4];
#pragma unroll
    for (int ni = 0; ni < 4; ++ni) {
      int col = ni * 16 + lr;
      bo[ni] = *(const bf16x8*)&omS[col * 32 + (kg ^ ((col & 6) >> 1)) * 8];
    }
    f32x4 pacc[2][4];
#pragma unroll
    for (int mi = 0; mi < 2; ++mi)
#pragma unroll
      for (int ni = 0; ni < 4; ++ni) {
        f32x4 z = 0.f;
        pacc[mi][ni] = __builtin_amdgcn_mfma_f32_16x16x32_bf16(af[mi], bo[ni], z, 0, 0, 0);
      }
    float sqv[2][4];
#pragma unroll
    for (int mi = 0; mi < 2; ++mi)
#pragma unroll
      for (int i = 0; i < 4; ++i)
        sqv[mi][i] = sqL[w * 32 + mi * 16 + kg * 4 + i];
#pragma unroll
    for (int mi = 0; mi < 2; ++mi)
#pragma unroll
      for (int ni = 0; ni < 4; ++ni) {
        u16 p4[4];
#pragma unroll
        for (int i = 0; i < 4; ++i)
          p4[i] = f2b(__expf(pacc[mi][ni][i] - sqv[mi][i]) * 0.125f);
        int m = ni * 16 + lr;
        int tok = w * 32 + mi * 16 + kg * 4;
        *(unsigned long long*)&pkT[m * 72 + tok] = *(const unsigned long long*)p4;
      }
    __syncthreads();

    {
      int ktok = w * 32;
      bf16x8 a2[4], b2v[3];
#pragma unroll
      for (int mi = 0; mi < 4; ++mi)
        a2[mi] = *(const bf16x8*)&pkT[(mi * 16 + lr) * 72 + ktok + kg * 8];
#pragma unroll
      for (int ni = 0; ni < 3; ++ni)
        b2v[ni] = *(const bf16x8*)&vT[(ni * 16 + lr) * 72 + ktok + kg * 8];
#pragma unroll
      for (int mi = 0; mi < 4; ++mi)
#pragma unroll
        for (int ni = 0; ni < 3; ++ni)
          kacc[mi][ni] = __builtin_amdgcn_mfma_f32_16x16x32_bf16(a2[mi], b2v[ni], kacc[mi][ni], 0, 0, 0);
    }
  }

  __syncthreads();
#pragma unroll
  for (int mi = 0; mi < 4; ++mi) {
#pragma unroll
    for (int ni = 0; ni < 3; ++ni) {
      if (ni < 2) {
#pragma unroll
        for (int i = 0; i < 4; ++i)
          red[w * 2112 + (mi * 16 + kg * 4 + i) * 33 + ni * 16 + lr] = kacc[mi][ni][i];
      } else if (lr == 0) {
#pragma unroll
        for (int i = 0; i < 4; ++i)
          red[w * 2112 + (mi * 16 + kg * 4 + i) * 33 + 32] = kacc[mi][2][i];
      }
    }
  }
  __syncthreads();
  float* dst = part + (size_t)(bh * KSPLIT + split) * 2112;
  for (int idx = t; idx < 2112; idx += 256) {
    int m, c;
    if (idx < 2048) { m = idx >> 5; c = idx & 31; }
    else            { m = idx - 2048; c = 32; }
    float s = 0.f;
#pragma unroll
    for (int w4 = 0; w4 < 4; ++w4) s += red[w4 * 2112 + m * 33 + c];
    dst[idx] = s;
  }
}

// ---------------------------------------------------------------------------
// Merged weight prep (r16, unchanged).
struct TJob { const float* s; u16* d; int lds, ldd, rows, cols; };
struct PrepArgs {
  TJob j[18];
  const float* omega; u16* wphiT; u16* omT;
  const float* bk; const float* bv; const float* bq; float* bias;
  const float* Wq; u16* WqOT; float* bqOm;
};
__global__ __launch_bounds__(256) void prep_kernel(PrepArgs P) {
  int t = threadIdx.x;
  const float SCALE = 0.4204482076268573f;
  if (blockIdx.y == 18) {
    for (int i = 0; i < 16; ++i) {
      int idx = (blockIdx.x * 256 + t) * 16 + i;
      int c = idx >> 8, k = idx & 255;
      float v = 0.f;
      if ((k >> 5) == (c >> 6)) v = P.omega[(k & 31) * 64 + (c & 63)] * SCALE;
      P.wphiT[idx] = f2b(v);
    }
    return;
  }
  if (blockIdx.y == 19) {
    if (blockIdx.x == 0) {
      for (int i = t; i < 2048; i += 256) {
        int m = i >> 5, k = i & 31;
        P.omT[i] = f2b(P.omega[k * 64 + m] * SCALE);
      }
    } else if (blockIdx.x == 1) {
      P.bias[t] = P.bk[t]; P.bias[256 + t] = P.bv[t]; P.bias[512 + t] = P.bq[t];
      P.bias[768 + t] = 0.f; P.bias[1024 + t] = 0.f;
    } else if (blockIdx.x == 2) {
      for (int c = t; c < 512; c += 256) {
        float s = 0.f;
        const int hb = (c >> 6) * 32, mm = c & 63;
        for (int d = 0; d < 32; ++d)
          s = __fmaf_rn(P.bq[hb + d], P.omega[d * 64 + mm], s);
        P.bqOm[c] = s * SCALE;
      }
    }
    return;
  }
  if (blockIdx.y == 20) {
    for (int i = 0; i < 16; ++i) {
      int idx = (blockIdx.x * 256 + t) * 16 + i;
      int c = idx >> 8, k = idx & 255;
      const int hb = (c >> 6) * 32, mm = c & 63;
      float s = 0.f;
      for (int d = 0; d < 32; ++d)
        s = __fmaf_rn(P.Wq[k * 256 + hb + d], P.omega[d * 64 + mm], s);
      P.WqOT[c * 256 + k] = f2b(s * SCALE);
    }
    return;
  }
  TJob jb = P.j[blockIdx.y];
  int ntc = jb.cols >> 6;
  int tile = blockIdx.x;
  if (tile >= (jb.rows >> 6) * ntc) return;
  int tr = (tile / ntc) << 6, tc = (tile % ntc) << 6;
  __shared__ float sm[64][68];
#pragma unroll
  for (int i = 0; i < 4; ++i) {
    int idx = t + 256 * i;
    int r = idx >> 4, c = (idx & 15) * 4;
    float4 v = *(const float4*)&jb.s[(size_t)(tr + r) * jb.lds + tc + c];
    sm[r][c] = v.x; sm[r][c + 1] = v.y; sm[r][c + 2] = v.z; sm[r][c + 3] = v.w;
  }
  __syncthreads();
#pragma unroll
  for (int i = 0; i < 4; ++i) {
    int idx = t + 256 * i;
    int c = idx >> 4, r = (idx & 15) * 4;
    ushort4 p; p.x = f2b(sm[r][c]); p.y = f2b(sm[r + 1][c]);
    p.z = f2b(sm[r + 2][c]); p.w = f2b(sm[r + 3][c]);
    *(ushort4*)&jb.d[(size_t)(tc + c) * jb.ldd + tr + r] = p;
  }
}

// ---------------------------------------------------------------------------
// Merged kv reduce + kvbdA (unchanged).
__global__ __launch_bounds__(256) void kvred_kernel(const float* __restrict__ part,
                                                    float* __restrict__ fin,
                                                    u16* __restrict__ kb) {
  const int bid = blockIdx.x, t = threadIdx.x;
  if (bid < 64) {
    const int bh = bid;
    for (int idx = t; idx < 2112; idx += 256) {
      float s = 0.f;
#pragma unroll
      for (int sp = 0; sp < KSPLIT; ++sp) s += part[(size_t)(bh * KSPLIT + sp) * 2112 + idx];
      fin[(size_t)bh * 2112 + idx] = s;
    }
    return;
  }
  int idx = (bid - 64) * 256 + t;
  int b = idx >> 17, rem = idx & 131071;
  int kp = rem >> 8, d = rem & 255;
  float v = 0.f;
  if ((kp >> 6) == (d >> 5)) {
    const int bh = b * 8 + (kp >> 6);
    const int off = (kp & 63) * 32 + (d & 31);
#pragma unroll
    for (int sp = 0; sp < KSPLIT; ++sp) v += part[(size_t)(bh * KSPLIT + sp) * 2112 + off];
  }
  kb[idx] = f2b(v);
}

// ---------------------------------------------------------------------------
// LN1 -> bf16 ln out + bf16 x copy (unchanged).
__global__ __launch_bounds__(256) void ln_kernel3(const float* __restrict__ x,
                                                  const float* __restrict__ g,
                                                  const float* __restrict__ b,
                                                  u16* __restrict__ out,
                                                  u16* __restrict__ xb) {
  const int row = blockIdx.x * 4 + (threadIdx.x >> 6);
  const int lane = threadIdx.x & 63;
  const float4 v = *(const float4*)&x[(size_t)row * 256 + lane * 4];
  ushort4 xo;
  xo.x = f2b(v.x); xo.y = f2b(v.y); xo.z = f2b(v.z); xo.w = f2b(v.w);
  *(ushort4*)&xb[(size_t)row * 256 + lane * 4] = xo;
  float s = v.x + v.y + v.z + v.w;
  float s2 = v.x * v.x + v.y * v.y + v.z * v.z + v.w * v.w;
#pragma unroll
  for (int off = 1; off < 64; off <<= 1) {
    s += __shfl_xor(s, off);
    s2 += __shfl_xor(s2, off);
  }
  const float mu = s * (1.f / 256.f);
  const float var = s2 * (1.f / 256.f) - mu * mu;
  const float rs = rsqrtf(var + 1e-3f);
  const float4 gv = *(const float4*)&g[lane * 4];
  const float4 bv = *(const float4*)&b[lane * 4];
  ushort4 o;
  o.x = f2b(gv.x * (v.x - mu) * rs + bv.x);
  o.y = f2b(gv.y * (v.y - mu) * rs + bv.y);
  o.z = f2b(gv.z * (v.z - mu) * rs + bv.z);
  o.w = f2b(gv.w * (v.w - mu) * rs + bv.w);
  *(ushort4*)&out[(size_t)row * 256 + lane * 4] = o;
}

// ---------------------------------------------------------------------------
extern "C" void kernel_launch(void* const* d_in, const int* in_sizes, int n_in,
                              void* d_out, int out_size, void* d_ws, size_t ws_size,
                              hipStream_t stream) {
  (void)in_sizes; (void)n_in; (void)out_size; (void)ws_size;
  const float* x     = (const float*)d_in[0];
  const float* ln1_g = (const float*)d_in[1];
  const float* ln1_b = (const float*)d_in[2];
  const float* Wq    = (const float*)d_in[3];
  const float* bq    = (const float*)d_in[4];
  const float* Wk    = (const float*)d_in[5];
  const float* bk    = (const float*)d_in[6];
  const float* Wv    = (const float*)d_in[7];
  const float* bv    = (const float*)d_in[8];
  const float* Wo    = (const float*)d_in[9];
  const float* bo    = (const float*)d_in[10];
  const float* omega = (const float*)d_in[11];
  const float* g1_Wr = (const float*)d_in[12];
  const float* g1_Ur = (const float*)d_in[13];
  const float* g1_Wz = (const float*)d_in[14];
  const float* g1_Uz = (const float*)d_in[15];
  const float* g1_Wg = (const float*)d_in[16];
  const float* g1_Ug = (const float*)d_in[17];
  const float* g1_bg = (const float*)d_in[18];
  const float* ln2_g = (const float*)d_in[19];
  const float* ln2_b = (const float*)d_in[20];
  const float* W1    = (const float*)d_in[21];
  const float* b1    = (const float*)d_in[22];
  const float* W2    = (const float*)d_in[23];
  const float* b2    = (const float*)d_in[24];
  const float* g2_Wr = (const float*)d_in[25];
  const float* g2_Ur = (const float*)d_in[26];
  const float* g2_Wz = (const float*)d_in[27];
  const float* g2_Uz = (const float*)d_in[28];
  const float* g2_Wg = (const float*)d_in[29];
  const float* g2_Ug = (const float*)d_in[30];
  const float* g2_bg = (const float*)d_in[31];

  const size_t SZB = (size_t)BN * 256;
  u16* S0 = (u16*)d_ws;            // ln1h -> ln2h
  u16* S1 = S0 + SZB;              // K -> y2
  u16* S2 = S1 + SZB;              // V -> rx2
  u16* S3 = S2 + SZB;              // y1 -> out1
  u16* qkvT  = S3 + SZB;
  u16* wphiT = qkvT + 768 * 256;
  u16* woT   = wphiT + 512 * 256;
  u16* g1rzT = woT + 65536;
  u16* g1hpT = g1rzT + 262144;
  u16* w1T   = g1hpT + 131072;
  u16* w2T   = w1T + 131072;
  u16* g2rzT = w2T + 131072;
  u16* g2hpT = g2rzT + 262144;
  u16* kvbdA = g2hpT + 131072;     // [8][512][256]
  u16* WoKVT = kvbdA + 1048576;    // [8][256][512]
  u16* omTg  = WoKVT + 1048576;
  u16* WqOT  = omTg + 2048;        // [512][256]
  float* bias768 = (float*)(WqOT + 131072);
  float* zero512 = bias768 + 768;
  float* bqOm    = bias768 + 1280;
  float* kvpart  = bqOm + 512;
  float* kvfin   = kvpart + (size_t)64 * KSPLIT * 2112;
  float* sqQ     = kvfin + 64 * 2112;
  u16* xb        = (u16*)(sqQ + (size_t)BN * 8);
  u16* db = (u16*)d_out;
  float* outf = (float*)d_out;

  dim3 blk(256), blkG(512);
  dim3 g1c(1, BN / 256), g2c(2, BN / 256), g3c(3, BN / 256);

  PrepArgs P;
  auto job = [](const float* s, u16* d, int lds, int ldd, int r, int c) {
    TJob t; t.s = s; t.d = d; t.lds = lds; t.ldd = ldd; t.rows = r; t.cols = c; return t;
  };
  P.j[0]  = job(Wk, qkvT, 256, 256, 256, 256);
  P.j[1]  = job(Wv, qkvT + 256 * 256, 256, 256, 256, 256);
  P.j[2]  = job(Wq, qkvT + 512 * 256, 256, 256, 256, 256);
  P.j[3]  = job(Wo, woT, 256, 256, 256, 256);
  P.j[4]  = job(g1_Wr, g1rzT, 256, 512, 256, 256);
  P.j[5]  = job(g1_Ur, g1rzT + 256, 256, 512, 256, 256);
  P.j[6]  = job(g1_Wz, g1rzT + 256 * 512, 256, 512, 256, 256);
  P.j[7]  = job(g1_Uz, g1rzT + 256 * 512 + 256, 256, 512, 256, 256);
  P.j[8]  = job(g1_Wg, g1hpT, 256, 512, 256, 256);
  P.j[9]  = job(g1_Ug, g1hpT + 256, 256, 512, 256, 256);
  P.j[10] = job(W1, w1T, 512, 256, 256, 512);
  P.j[11] = job(W2, w2T, 256, 512, 512, 256);
  P.j[12] = job(g2_Wr, g2rzT, 256, 512, 256, 256);
  P.j[13] = job(g2_Ur, g2rzT + 256, 256, 512, 256, 256);
  P.j[14] = job(g2_Wz, g2rzT + 256 * 512, 256, 512, 256, 256);
  P.j[15] = job(g2_Uz, g2rzT + 256 * 512 + 256, 256, 512, 256, 256);
  P.j[16] = job(g2_Wg, g2hpT, 256, 512, 256, 256);
  P.j[17] = job(g2_Ug, g2hpT + 256, 256, 512, 256, 256);
  P.omega = omega; P.wphiT = wphiT; P.omT = omTg;
  P.bk = bk; P.bv = bv; P.bq = bq; P.bias = bias768;
  P.Wq = Wq; P.WqOT = WqOT; P.bqOm = bqOm;
  prep_kernel<<<dim3(32, 21), blk, 0, stream>>>(P);

  // ---- attention ----
  ln_kernel3<<<BN / 4, blk, 0, stream>>>(x, ln1_g, ln1_b, S0, xb);
  gemm2<7,0,0,0><<<g3c, blkG, 0, stream>>>(S0, 256, S0, 256, qkvT, 256,
      bias768, nullptr, nullptr, sqQ, S1, S2, nullptr, 256, 256);   // K,V + sqQ
  fkv_kernel<<<dim3(64, KSPLIT), blk, 0, stream>>>(S1, S2, omTg, kvpart);
  kvred_kernel<<<4160, blk, 0, stream>>>(kvpart, kvfin, kvbdA);
  // WoKVT[b] = Wo^T @ kvbd_b^T : M=2048 (8 tiles of 256, A rows wrap), Nc=512
  gemm2<0,0,0,2><<<dim3(2, 8), blkG, 0, stream>>>(woT, 256, woT, 256, kvbdA, 256,
      zero512, nullptr, nullptr, nullptr, WoKVT, nullptr, nullptr, 512, 256);
  // pq from ln1h (+fused den) -> db
  gemm2<10,0,0,0><<<g2c, blkG, 0, stream>>>(S0, 256, S0, 256, WqOT, 256,
      bqOm, kvfin, nullptr, sqQ, db, nullptr, nullptr, 512, 256);
  gemm2<0,0,0,1><<<g1c, blkG, 0, stream>>>(db, 512, db + 256, 512, WoKVT, 512,
      bo, nullptr, nullptr, nullptr, S3, nullptr, nullptr, 256, 512);   // y1 -> S3
  // ---- gate 1 (y=y1(S3), x=xb) ----
  gemm2<8,1,0,0><<<g2c, blkG, 0, stream>>>(S3, 256, xb, 256, g1rzT, 512,
      g1_bg, xb, nullptr, nullptr, db, db + SZB, nullptr, 256, 512);    // rx1, z1
  gemm2<9,1,0,0><<<g1c, blkG, 0, stream>>>(S3, 256, db, 256, g1hpT, 512,
      ln2_g, xb, db + SZB, ln2_b, S3, S0, nullptr, 256, 512);           // out1, ln2h
  // ---- MLP ----
  gemm2<1,0,0,0><<<g2c, blkG, 0, stream>>>(S0, 256, S0, 256, w1T, 256,
      b1, nullptr, nullptr, nullptr, db, nullptr, nullptr, 512, 256);   // hid -> db
  gemm2<1,0,0,0><<<g1c, blkG, 0, stream>>>(db, 512, db + 256, 512, w2T, 512,
      b2, nullptr, nullptr, nullptr, S1, nullptr, nullptr, 256, 512);   // y2 -> S1
  // ---- gate 2 (y=y2(S1), x=out1(S3)) ----
  gemm2<8,1,0,0><<<g2c, blkG, 0, stream>>>(S1, 256, S3, 256, g2rzT, 512,
      g2_bg, S3, nullptr, nullptr, S2, S0, nullptr, 256, 512);          // rx2, z2
  gemm2<4,1,1,0><<<g1c, blkG, 0, stream>>>(S1, 256, S2, 256, g2hpT, 512,
      nullptr, S3, S0, nullptr, outf, nullptr, nullptr, 256, 512);      // final
}

// Round 18
// 534.440 us; speedup vs baseline: 1.4583x; 1.4583x over previous
//
#include <hip/hip_runtime.h>

#define B_ 8
#define N_ 8192
#define H_ 8
#define KSPLIT 16
#define BN 65536  // B_*N_

typedef float f32x4 __attribute__((ext_vector_type(4)));
typedef __bf16 bf16x8 __attribute__((ext_vector_type(8)));
typedef unsigned short u16;

__device__ __forceinline__ u16 f2b(float f) {
  union { float f; unsigned u; } v; v.f = f;
  return (u16)((v.u + 0x7fffu + ((v.u >> 16) & 1u)) >> 16);
}
__device__ __forceinline__ float b2f(u16 u) {
  union { unsigned u; float f; } v; v.u = ((unsigned)u) << 16;
  return v.f;
}

// async global->LDS 16B
__device__ __forceinline__ void gload16(const void* g, const void* lds) {
  __builtin_amdgcn_global_load_lds(
      (const __attribute__((address_space(1))) unsigned int*)(unsigned long long)g,
      (__attribute__((address_space(3))) unsigned int*)(unsigned long long)lds,
      16, 0, 0);
}

__device__ __forceinline__ void ld16f(const float* p, float* f) {
#pragma unroll
  for (int j = 0; j < 4; ++j) {
    float4 q = *(const float4*)(p + j * 4);
    f[j * 4 + 0] = q.x; f[j * 4 + 1] = q.y; f[j * 4 + 2] = q.z; f[j * 4 + 3] = q.w;
  }
}
__device__ __forceinline__ void ld16b(const u16* p, float* f) {
  uint4 a = *(const uint4*)p, b = *(const uint4*)(p + 8);
  const unsigned uu[8] = {a.x, a.y, a.z, a.w, b.x, b.y, b.z, b.w};
#pragma unroll
  for (int j = 0; j < 8; ++j) {
    f[2 * j]     = b2f((u16)(uu[j] & 0xffff));
    f[2 * j + 1] = b2f((u16)(uu[j] >> 16));
  }
}
__device__ __forceinline__ void st16b(u16* p, const float* f) {
  u16 o[16];
#pragma unroll
  for (int j = 0; j < 16; ++j) o[j] = f2b(f[j]);
  *(uint4*)p = *(const uint4*)o;
  *(uint4*)(p + 8) = *(const uint4*)(o + 8);
}
__device__ __forceinline__ void st16f(float* p, const float* f) {
#pragma unroll
  for (int j = 0; j < 4; ++j) {
    float4 q; q.x = f[j * 4]; q.y = f[j * 4 + 1]; q.z = f[j * 4 + 2]; q.w = f[j * 4 + 3];
    *(float4*)(p + j * 4) = q;
  }
}

// ---------------------------------------------------------------------------
// bf16 MFMA GEMM, 128x256 tile, 512 threads (8 waves = 2x4 of 64x64), BK=32,
// ring-3 LDS, single barrier per K-step, counted vmcnt (r11-proven core).
// MODE 0: bf16 C = acc + bias[col]
// MODE 1: bf16 C = relu(acc + bias[col])
// MODE 4: C = (1-z)*X + z*tanh(acc); z=auxZ bf16, X per XBF; CF32 -> f32 C
// MODE 7: QKV split {Cv,Cv2,Cv3}; + per-head sq of Q (colBase 512) -> auxS
// MODE 8: rz: colBase==0 -> Cv = sigmoid(acc)*X ; ==256 -> Cv2 = sigmoid(acc-bias)
// MODE 9: gate-combine -> Cv ; + row-LN (g=bias, b=auxS) -> ln2h Cv2. Nc=256.
// MODE 10: pq+den: vv = exp(acc-sq)*0.125; den_h via 4-thread shfl vs s
//          (auxX=kvfin); store vv/den.
// BSEL 1: BT += (rowBase>>13)*131072 ; BSEL 2: BT += (rowBase>>8)*131072,
//          A row wraps mod 256 (WoKVT prep).
// ---------------------------------------------------------------------------
template <int MODE, int XBF, int CF32, int BSEL>
__global__ __launch_bounds__(512) void gemm2(
    const u16* __restrict__ A1, int lda1, const u16* __restrict__ A2, int lda2,
    const u16* __restrict__ BT, int ldb,
    const float* __restrict__ bias, const void* __restrict__ auxX,
    const u16* __restrict__ auxZ, const float* __restrict__ auxS,
    void* __restrict__ Cv, void* __restrict__ Cv2, void* __restrict__ Cv3,
    int ldc, int K) {
  __shared__ __align__(16) u16 As[3][4096];   // 128x32 bf16 per buf
  __shared__ __align__(16) u16 Bs[3][8192];   // 256x32 bf16 per buf
  const int t = threadIdx.x, lane = t & 63, w = t >> 6;  // w in 0..7
  const int nwg = gridDim.x * gridDim.y;
  const int flat = blockIdx.x + gridDim.x * blockIdx.y;
  const int wg = (flat & 7) * (nwg >> 3) + (flat >> 3);  // XCD-aware remap
  const int bx = wg % gridDim.x, by = wg / gridDim.x;
  const int rowBase = by * 128, colBase = bx * 256;
  const int aBase = (BSEL == 2) ? (rowBase & 255) : rowBase;
  const u16* BTb = BT;
  if (BSEL == 1) BTb = BT + (size_t)(rowBase >> 13) * 131072;
  if (BSEL == 2) BTb = BT + (size_t)(rowBase >> 8) * 131072;

  const int lr = lane & 15, kg = lane >> 4;
  const int wrow = (w >> 2) * 64, wcol = (w & 3) * 64;

  f32x4 acc[4][4];
#pragma unroll
  for (int m = 0; m < 4; ++m)
#pragma unroll
    for (int n = 0; n < 4; ++n) acc[m][n] = 0.f;

  const int nt = K >> 5;
  auto stage = [&](int s) {  // 3 gload16 per thread
    const int buf = s % 3;
    const int k0 = s << 5;
    const u16* Ap; int la, ka;
    if (k0 < 256) { Ap = A1; la = lda1; ka = k0; }
    else          { Ap = A2; la = lda2; ka = k0 - 256; }
    {
      int row = t >> 2, sl = t & 3;
      int ks = (sl ^ ((row & 6) >> 1)) * 8;
      gload16(&Ap[(size_t)(aBase + row) * la + ka + ks], &As[buf][t * 8]);
    }
#pragma unroll
    for (int j = 0; j < 2; ++j) {
      int slot = j * 512 + t;
      int col = slot >> 2, sl = slot & 3;
      int ks = (sl ^ ((col & 6) >> 1)) * 8;
      gload16(&BTb[(size_t)(colBase + col) * ldb + k0 + ks], &Bs[buf][slot * 8]);
    }
  };

  auto lbar = [&]() {
    asm volatile("s_waitcnt lgkmcnt(0)" ::: "memory");
    __builtin_amdgcn_sched_barrier(0);
    __builtin_amdgcn_s_barrier();
    __builtin_amdgcn_sched_barrier(0);
  };

  stage(0);
  stage(1);
  for (int s = 0; s < nt; ++s) {
    const int buf = s % 3;
    if (nt - s > 1) asm volatile("s_waitcnt vmcnt(3)" ::: "memory");
    else            asm volatile("s_waitcnt vmcnt(0)" ::: "memory");
    __builtin_amdgcn_sched_barrier(0);
    __builtin_amdgcn_s_barrier();
    __builtin_amdgcn_sched_barrier(0);
    if (s + 2 < nt) stage(s + 2);
    bf16x8 af[4], bf[4];
#pragma unroll
    for (int m = 0; m < 4; ++m) {
      int row = wrow + m * 16 + lr;
      af[m] = *(const bf16x8*)&As[buf][row * 32 + (kg ^ ((row & 6) >> 1)) * 8];
    }
#pragma unroll
    for (int n = 0; n < 4; ++n) {
      int col = wcol + n * 16 + lr;
      bf[n] = *(const bf16x8*)&Bs[buf][col * 32 + (kg ^ ((col & 6) >> 1)) * 8];
    }
    __builtin_amdgcn_s_setprio(1);
#pragma unroll
    for (int m = 0; m < 4; ++m)
#pragma unroll
      for (int n = 0; n < 4; ++n)
        acc[m][n] = __builtin_amdgcn_mfma_f32_16x16x32_bf16(af[m], bf[n], acc[m][n], 0, 0, 0);
    __builtin_amdgcn_s_setprio(0);
  }

  // ---- epilogue: repack via scr (aliased over Bs; vmem fully drained) ----
  lbar();
  float* scr = (float*)&Bs[0][0];  // 32 x 260 f32
#pragma unroll
  for (int m = 0; m < 4; ++m) {
    if (m) lbar();
#pragma unroll
    for (int n = 0; n < 4; ++n)
#pragma unroll
      for (int i = 0; i < 4; ++i)
        scr[((w >> 2) * 16 + kg * 4 + i) * 260 + wcol + n * 16 + lr] = acc[m][n][i];
    lbar();
    const int sr = t >> 4, cs = (t & 15) * 16;
    const int grow = rowBase + (sr >> 4) * 64 + m * 16 + (sr & 15);
    const int gcol = colBase + cs;
    float vv[16];
#pragma unroll
    for (int j = 0; j < 4; ++j) {
      float4 q = *(const float4*)&scr[sr * 260 + cs + j * 4];
      vv[j * 4] = q.x; vv[j * 4 + 1] = q.y; vv[j * 4 + 2] = q.z; vv[j * 4 + 3] = q.w;
    }
    if (MODE == 0 || MODE == 1) {
      float bb[16]; ld16f(&bias[gcol], bb);
#pragma unroll
      for (int j = 0; j < 16; ++j) {
        vv[j] += bb[j];
        if (MODE == 1) vv[j] = fmaxf(vv[j], 0.f);
      }
      st16b(&((u16*)Cv)[(size_t)grow * ldc + gcol], vv);
    } else if (MODE == 10) {
      float sx = auxS[(size_t)grow * 8 + (gcol >> 6)];
#pragma unroll
      for (int j = 0; j < 16; ++j) vv[j] = __expf(vv[j] - sx) * 0.125f;
      const float* kvf = (const float*)auxX;  // kvfin
      float sv[16];
      ld16f(&kvf[((size_t)(grow >> 13) * 8 + (gcol >> 6)) * 2112 + 2048 + (gcol & 63)], sv);
      float dp = 0.f;
#pragma unroll
      for (int j = 0; j < 16; ++j) dp = __fmaf_rn(vv[j], sv[j], dp);
      dp += __shfl_xor(dp, 1);
      dp += __shfl_xor(dp, 2);
      const float r = 1.0f / dp;
#pragma unroll
      for (int j = 0; j < 16; ++j) vv[j] *= r;
      st16b(&((u16*)Cv)[(size_t)grow * ldc + gcol], vv);
    } else if (MODE == 7) {
      float bb[16]; ld16f(&bias[gcol], bb);
#pragma unroll
      for (int j = 0; j < 16; ++j) vv[j] += bb[j];
      u16* Cp; int c2;
      if (colBase < 256)      { Cp = (u16*)Cv;  c2 = gcol; }
      else if (colBase < 512) { Cp = (u16*)Cv2; c2 = gcol - 256; }
      else                    { Cp = (u16*)Cv3; c2 = gcol - 512; }
      st16b(&Cp[(size_t)grow * ldc + c2], vv);
      if (colBase == 512) {  // Q: per-head sq -> auxS (2 lanes per head)
        float s = 0.f;
#pragma unroll
        for (int j = 0; j < 16; ++j) s += vv[j] * vv[j];
        s += __shfl_xor(s, 1);
        if ((t & 1) == 0)
          const_cast<float*>(auxS)[(size_t)grow * 8 + ((gcol - 512) >> 5)] =
              0.0883883476483184f * s;
      }
    } else if (MODE == 8) {
      if (colBase < 256) {
        float xv[16];
        if (XBF) ld16b(&((const u16*)auxX)[(size_t)grow * 256 + gcol], xv);
        else     ld16f(&((const float*)auxX)[(size_t)grow * 256 + gcol], xv);
#pragma unroll
        for (int j = 0; j < 16; ++j) vv[j] = (1.f / (1.f + __expf(-vv[j]))) * xv[j];
        st16b(&((u16*)Cv)[(size_t)grow * ldc + gcol], vv);
      } else {
        float bb[16]; ld16f(&bias[gcol - 256], bb);
#pragma unroll
        for (int j = 0; j < 16; ++j) vv[j] = 1.f / (1.f + __expf(-(vv[j] - bb[j])));
        st16b(&((u16*)Cv2)[(size_t)grow * ldc + gcol - 256], vv);
      }
    } else if (MODE == 4) {
      float zz[16], xv[16];
      ld16b(&auxZ[(size_t)grow * 256 + gcol], zz);
      if (XBF) ld16b(&((const u16*)auxX)[(size_t)grow * 256 + gcol], xv);
      else     ld16f(&((const float*)auxX)[(size_t)grow * 256 + gcol], xv);
#pragma unroll
      for (int j = 0; j < 16; ++j)
        vv[j] = (1.f - zz[j]) * xv[j] + zz[j] * tanhf(vv[j]);
      if (CF32) st16f(&((float*)Cv)[(size_t)grow * ldc + gcol], vv);
      else      st16b(&((u16*)Cv)[(size_t)grow * ldc + gcol], vv);
    } else if (MODE == 9) {
      float zz[16], xv[16];
      ld16b(&auxZ[(size_t)grow * 256 + gcol], zz);
      ld16b(&((const u16*)auxX)[(size_t)grow * 256 + gcol], xv);
#pragma unroll
      for (int j = 0; j < 16; ++j)
        vv[j] = (1.f - zz[j]) * xv[j] + zz[j] * tanhf(vv[j]);
      st16b(&((u16*)Cv)[(size_t)grow * 256 + gcol], vv);
      float s1 = 0.f, s2 = 0.f;
#pragma unroll
      for (int j = 0; j < 16; ++j) { s1 += vv[j]; s2 += vv[j] * vv[j]; }
#pragma unroll
      for (int off = 1; off < 16; off <<= 1) {
        s1 += __shfl_xor(s1, off);
        s2 += __shfl_xor(s2, off);
      }
      float mu = s1 * (1.f / 256.f);
      float var = s2 * (1.f / 256.f) - mu * mu;
      float rs = rsqrtf(var + 1e-3f);
      float gg[16], bb2[16];
      ld16f(&bias[gcol], gg);
      ld16f(&auxS[gcol], bb2);
#pragma unroll
      for (int j = 0; j < 16; ++j) vv[j] = gg[j] * (vv[j] - mu) * rs + bb2[j];
      st16b(&((u16*)Cv2)[(size_t)grow * 256 + gcol], vv);
    }
  }
}

// ---------------------------------------------------------------------------
// Fused phi_k + sq + kv kernel (unchanged, proven).
// ---------------------------------------------------------------------------
__global__ __launch_bounds__(256) void fkv_kernel(const u16* __restrict__ Kb,
                                                  const u16* __restrict__ Vb,
                                                  const u16* __restrict__ omT,
                                                  float* __restrict__ part) {
  __shared__ __align__(16) char smem[33792];
  u16* Ks  = (u16*)smem;
  u16* omS = Ks + 4096;
  u16* pkT = omS + 2048;
  u16* vT  = pkT + 64 * 72;
  float* sqL = (float*)(vT + 48 * 72);
  float* red = (float*)smem;

  const int bh = blockIdx.x, split = blockIdx.y;
  const int b = bh >> 3, h = bh & 7;
  const int t = threadIdx.x, lane = t & 63, w = t >> 6;
  const int lr = lane & 15, kg = lane >> 4;
  const size_t rbase = (size_t)b * N_ + (size_t)split * (N_ / KSPLIT);

  {
    int m = t >> 2, sl = t & 3;
    gload16(&omT[m * 32 + ((sl ^ ((m & 6) >> 1)) * 8)], &omS[t * 8]);
  }
  for (int i = t; i < 16 * 128; i += 256) {
    int r = 32 + (i >> 7), tok = i & 127;
    vT[r * 72 + tok] = (r == 32) ? (u16)0x3f80 : (u16)0;
  }

  f32x4 kacc[4][3];
#pragma unroll
  for (int mi = 0; mi < 4; ++mi)
#pragma unroll
    for (int ni = 0; ni < 3; ++ni) kacc[mi][ni] = 0.f;

  for (int tile = 0; tile < (N_ / KSPLIT) / 128; ++tile) {
    __syncthreads();
    const size_t gt0 = rbase + tile * 128;
#pragma unroll
    for (int j = 0; j < 2; ++j) {
      int slot = j * 256 + t;
      int tok = slot >> 2, sl = slot & 3;
      gload16(&Kb[(gt0 + tok) * 256 + h * 32 + ((sl ^ ((tok & 6) >> 1)) * 8)],
              &Ks[slot * 8]);
    }
#pragma unroll
    for (int j = 0; j < 2; ++j) {
      int slot = j * 256 + t;
      int tok = slot >> 2, seg = slot & 3;
      uint4 q = *(const uint4*)&Vb[(gt0 + tok) * 256 + h * 32 + seg * 8];
      const unsigned uu[4] = {q.x, q.y, q.z, q.w};
#pragma unroll
      for (int jj = 0; jj < 4; ++jj) {
        vT[(seg * 8 + jj * 2 + 0) * 72 + tok] = (u16)(uu[jj] & 0xffffu);
        vT[(seg * 8 + jj * 2 + 1) * 72 + tok] = (u16)(uu[jj] >> 16);
      }
    }
    asm volatile("s_waitcnt vmcnt(0)" ::: "memory");
    __syncthreads();

    uint4 araw[2];
    bf16x8 af[2];
#pragma unroll
    for (int mi = 0; mi < 2; ++mi) {
      int row = w * 32 + mi * 16 + lr;
      araw[mi] = *(const uint4*)&Ks[row * 32 + (kg ^ ((row & 6) >> 1)) * 8];
      af[mi] = *(const bf16x8*)&araw[mi];
    }
#pragma unroll
    for (int mi = 0; mi < 2; ++mi) {
      const unsigned uu[4] = {araw[mi].x, araw[mi].y, araw[mi].z, araw[mi].w};
      float s = 0.f;
#pragma unroll
      for (int j = 0; j < 4; ++j) {
        float lo = b2f((u16)(uu[j] & 0xffffu)), hi = b2f((u16)(uu[j] >> 16));
        s = __fmaf_rn(lo, lo, s); s = __fmaf_rn(hi, hi, s);
      }
      s += __shfl_xor(s, 16);
      s += __shfl_xor(s, 32);
      if (lane < 16) sqL[w * 32 + mi * 16 + lr] = 0.0883883476483184f * s;
    }
    bf16x8 bo[4];
#pragma unroll
    for (int ni = 0; ni < 4; ++ni) {
      int col = ni * 16 + lr;
      bo[ni] = *(const bf16x8*)&omS[col * 32 + (kg ^ ((col & 6) >> 1)) * 8];
    }
    f32x4 pacc[2][4];
#pragma unroll
    for (int mi = 0; mi < 2; ++mi)
#pragma unroll
      for (int ni = 0; ni < 4; ++ni) {
        f32x4 z = 0.f;
        pacc[mi][ni] = __builtin_amdgcn_mfma_f32_16x16x32_bf16(af[mi], bo[ni], z, 0, 0, 0);
      }
    float sqv[2][4];
#pragma unroll
    for (int mi = 0; mi < 2; ++mi)
#pragma unroll
      for (int i = 0; i < 4; ++i)
        sqv[mi][i] = sqL[w * 32 + mi * 16 + kg * 4 + i];
#pragma unroll
    for (int mi = 0; mi < 2; ++mi)
#pragma unroll
      for (int ni = 0; ni < 4; ++ni) {
        u16 p4[4];
#pragma unroll
        for (int i = 0; i < 4; ++i)
          p4[i] = f2b(__expf(pacc[mi][ni][i] - sqv[mi][i]) * 0.125f);
        int m = ni * 16 + lr;
        int tok = w * 32 + mi * 16 + kg * 4;
        *(unsigned long long*)&pkT[m * 72 + tok] = *(const unsigned long long*)p4;
      }
    __syncthreads();

    {
      int ktok = w * 32;
      bf16x8 a2[4], b2v[3];
#pragma unroll
      for (int mi = 0; mi < 4; ++mi)
        a2[mi] = *(const bf16x8*)&pkT[(mi * 16 + lr) * 72 + ktok + kg * 8];
#pragma unroll
      for (int ni = 0; ni < 3; ++ni)
        b2v[ni] = *(const bf16x8*)&vT[(ni * 16 + lr) * 72 + ktok + kg * 8];
#pragma unroll
      for (int mi = 0; mi < 4; ++mi)
#pragma unroll
        for (int ni = 0; ni < 3; ++ni)
          kacc[mi][ni] = __builtin_amdgcn_mfma_f32_16x16x32_bf16(a2[mi], b2v[ni], kacc[mi][ni], 0, 0, 0);
    }
  }

  __syncthreads();
#pragma unroll
  for (int mi = 0; mi < 4; ++mi) {
#pragma unroll
    for (int ni = 0; ni < 3; ++ni) {
      if (ni < 2) {
#pragma unroll
        for (int i = 0; i < 4; ++i)
          red[w * 2112 + (mi * 16 + kg * 4 + i) * 33 + ni * 16 + lr] = kacc[mi][ni][i];
      } else if (lr == 0) {
#pragma unroll
        for (int i = 0; i < 4; ++i)
          red[w * 2112 + (mi * 16 + kg * 4 + i) * 33 + 32] = kacc[mi][2][i];
      }
    }
  }
  __syncthreads();
  float* dst = part + (size_t)(bh * KSPLIT + split) * 2112;
  for (int idx = t; idx < 2112; idx += 256) {
    int m, c;
    if (idx < 2048) { m = idx >> 5; c = idx & 31; }
    else            { m = idx - 2048; c = 32; }
    float s = 0.f;
#pragma unroll
    for (int w4 = 0; w4 < 4; ++w4) s += red[w4 * 2112 + m * 33 + c];
    dst[idx] = s;
  }
}

// ---------------------------------------------------------------------------
// Merged weight prep: y<18 -> transpose job; y==18 -> wphiT; y==19 -> omT+bias
struct TJob { const float* s; u16* d; int lds, ldd, rows, cols; };
struct PrepArgs {
  TJob j[18];
  const float* omega; u16* wphiT; u16* omT;
  const float* bk; const float* bv; const float* bq; float* bias;
};
__global__ __launch_bounds__(256) void prep_kernel(PrepArgs P) {
  int t = threadIdx.x;
  if (blockIdx.y == 18) {  // wphiT: 512*256 elems, 32 blocks x 16/thread
    for (int i = 0; i < 16; ++i) {
      int idx = (blockIdx.x * 256 + t) * 16 + i;
      int c = idx >> 8, k = idx & 255;
      float v = 0.f;
      if ((k >> 5) == (c >> 6)) v = P.omega[(k & 31) * 64 + (c & 63)] * 0.4204482076268573f;
      P.wphiT[idx] = f2b(v);
    }
    return;
  }
  if (blockIdx.y == 19) {
    if (blockIdx.x == 0) {  // omT: 2048 elems
      for (int i = t; i < 2048; i += 256) {
        int m = i >> 5, k = i & 31;
        P.omT[i] = f2b(P.omega[k * 64 + m] * 0.4204482076268573f);
      }
    } else if (blockIdx.x == 1) {  // bias768 + zero512
      P.bias[t] = P.bk[t]; P.bias[256 + t] = P.bv[t]; P.bias[512 + t] = P.bq[t];
      P.bias[768 + t] = 0.f; P.bias[1024 + t] = 0.f;
    }
    return;
  }
  TJob jb = P.j[blockIdx.y];
  int ntc = jb.cols >> 6;
  int tile = blockIdx.x;
  if (tile >= (jb.rows >> 6) * ntc) return;
  int tr = (tile / ntc) << 6, tc = (tile % ntc) << 6;
  __shared__ float sm[64][68];
#pragma unroll
  for (int i = 0; i < 4; ++i) {
    int idx = t + 256 * i;
    int r = idx >> 4, c = (idx & 15) * 4;
    float4 v = *(const float4*)&jb.s[(size_t)(tr + r) * jb.lds + tc + c];
    sm[r][c] = v.x; sm[r][c + 1] = v.y; sm[r][c + 2] = v.z; sm[r][c + 3] = v.w;
  }
  __syncthreads();
#pragma unroll
  for (int i = 0; i < 4; ++i) {
    int idx = t + 256 * i;
    int c = idx >> 4, r = (idx & 15) * 4;
    ushort4 p; p.x = f2b(sm[r][c]); p.y = f2b(sm[r + 1][c]);
    p.z = f2b(sm[r + 2][c]); p.w = f2b(sm[r + 3][c]);
    *(ushort4*)&jb.d[(size_t)(tc + c) * jb.ldd + tr + r] = p;
  }
}

// ---------------------------------------------------------------------------
// Merged kv reduce + kvbdA: bid<64 -> kvfin; bid>=64 -> kvbdA from kvpart.
__global__ __launch_bounds__(256) void kvred_kernel(const float* __restrict__ part,
                                                    float* __restrict__ fin,
                                                    u16* __restrict__ kb) {
  const int bid = blockIdx.x, t = threadIdx.x;
  if (bid < 64) {
    const int bh = bid;
    for (int idx = t; idx < 2112; idx += 256) {
      float s = 0.f;
#pragma unroll
      for (int sp = 0; sp < KSPLIT; ++sp) s += part[(size_t)(bh * KSPLIT + sp) * 2112 + idx];
      fin[(size_t)bh * 2112 + idx] = s;
    }
    return;
  }
  int idx = (bid - 64) * 256 + t;  // 8*512*256 elems, 4096 blocks
  int b = idx >> 17, rem = idx & 131071;
  int kp = rem >> 8, d = rem & 255;
  float v = 0.f;
  if ((kp >> 6) == (d >> 5)) {
    const int bh = b * 8 + (kp >> 6);
    const int off = (kp & 63) * 32 + (d & 31);
#pragma unroll
    for (int sp = 0; sp < KSPLIT; ++sp) v += part[(size_t)(bh * KSPLIT + sp) * 2112 + off];
  }
  kb[idx] = f2b(v);
}

// ---------------------------------------------------------------------------
// LN1 (f32 in) -> bf16 ln out + bf16 x copy (xb). One wave per row.
__global__ __launch_bounds__(256) void ln_kernel3(const float* __restrict__ x,
                                                  const float* __restrict__ g,
                                                  const float* __restrict__ b,
                                                  u16* __restrict__ out,
                                                  u16* __restrict__ xb) {
  const int row = blockIdx.x * 4 + (threadIdx.x >> 6);
  const int lane = threadIdx.x & 63;
  const float4 v = *(const float4*)&x[(size_t)row * 256 + lane * 4];
  ushort4 xo;
  xo.x = f2b(v.x); xo.y = f2b(v.y); xo.z = f2b(v.z); xo.w = f2b(v.w);
  *(ushort4*)&xb[(size_t)row * 256 + lane * 4] = xo;
  float s = v.x + v.y + v.z + v.w;
  float s2 = v.x * v.x + v.y * v.y + v.z * v.z + v.w * v.w;
#pragma unroll
  for (int off = 1; off < 64; off <<= 1) {
    s += __shfl_xor(s, off);
    s2 += __shfl_xor(s2, off);
  }
  const float mu = s * (1.f / 256.f);
  const float var = s2 * (1.f / 256.f) - mu * mu;
  const float rs = rsqrtf(var + 1e-3f);
  const float4 gv = *(const float4*)&g[lane * 4];
  const float4 bv = *(const float4*)&b[lane * 4];
  ushort4 o;
  o.x = f2b(gv.x * (v.x - mu) * rs + bv.x);
  o.y = f2b(gv.y * (v.y - mu) * rs + bv.y);
  o.z = f2b(gv.z * (v.z - mu) * rs + bv.z);
  o.w = f2b(gv.w * (v.w - mu) * rs + bv.w);
  *(ushort4*)&out[(size_t)row * 256 + lane * 4] = o;
}

// ---------------------------------------------------------------------------
extern "C" void kernel_launch(void* const* d_in, const int* in_sizes, int n_in,
                              void* d_out, int out_size, void* d_ws, size_t ws_size,
                              hipStream_t stream) {
  (void)in_sizes; (void)n_in; (void)out_size; (void)ws_size;
  const float* x     = (const float*)d_in[0];
  const float* ln1_g = (const float*)d_in[1];
  const float* ln1_b = (const float*)d_in[2];
  const float* Wq    = (const float*)d_in[3];
  const float* bq    = (const float*)d_in[4];
  const float* Wk    = (const float*)d_in[5];
  const float* bk    = (const float*)d_in[6];
  const float* Wv    = (const float*)d_in[7];
  const float* bv    = (const float*)d_in[8];
  const float* Wo    = (const float*)d_in[9];
  const float* bo    = (const float*)d_in[10];
  const float* omega = (const float*)d_in[11];
  const float* g1_Wr = (const float*)d_in[12];
  const float* g1_Ur = (const float*)d_in[13];
  const float* g1_Wz = (const float*)d_in[14];
  const float* g1_Uz = (const float*)d_in[15];
  const float* g1_Wg = (const float*)d_in[16];
  const float* g1_Ug = (const float*)d_in[17];
  const float* g1_bg = (const float*)d_in[18];
  const float* ln2_g = (const float*)d_in[19];
  const float* ln2_b = (const float*)d_in[20];
  const float* W1    = (const float*)d_in[21];
  const float* b1    = (const float*)d_in[22];
  const float* W2    = (const float*)d_in[23];
  const float* b2    = (const float*)d_in[24];
  const float* g2_Wr = (const float*)d_in[25];
  const float* g2_Ur = (const float*)d_in[26];
  const float* g2_Wz = (const float*)d_in[27];
  const float* g2_Uz = (const float*)d_in[28];
  const float* g2_Wg = (const float*)d_in[29];
  const float* g2_Ug = (const float*)d_in[30];
  const float* g2_bg = (const float*)d_in[31];

  const size_t SZB = (size_t)BN * 256;
  u16* S0 = (u16*)d_ws;            // ln1h -> ln2h
  u16* S1 = S0 + SZB;              // K -> y2
  u16* S2 = S1 + SZB;              // V -> rx2
  u16* S3 = S2 + SZB;              // Q -> y1 -> out1
  u16* qkvT  = S3 + SZB;
  u16* wphiT = qkvT + 768 * 256;
  u16* woT   = wphiT + 512 * 256;
  u16* g1rzT = woT + 65536;
  u16* g1hpT = g1rzT + 262144;
  u16* w1T   = g1hpT + 131072;
  u16* w2T   = w1T + 131072;
  u16* g2rzT = w2T + 131072;
  u16* g2hpT = g2rzT + 262144;
  u16* kvbdA = g2hpT + 131072;     // [8][512][256]
  u16* WoKVT = kvbdA + 1048576;    // [8][256][512]
  u16* omTg  = WoKVT + 1048576;
  float* bias768 = (float*)(omTg + 2048);  // 768 bias + 512 zeros
  float* zero512 = bias768 + 768;
  float* kvpart  = bias768 + 1280;
  float* kvfin   = kvpart + (size_t)64 * KSPLIT * 2112;
  float* sqQ     = kvfin + 64 * 2112;      // BN*8
  u16* xb        = (u16*)(sqQ + (size_t)BN * 8);  // bf16 x (33.5 MB)
  u16* db = (u16*)d_out;
  float* outf = (float*)d_out;

  dim3 blk(256), blkG(512);
  dim3 g1c(1, BN / 128), g2c(2, BN / 128), g3c(3, BN / 128);

  PrepArgs P;
  auto job = [](const float* s, u16* d, int lds, int ldd, int r, int c) {
    TJob t; t.s = s; t.d = d; t.lds = lds; t.ldd = ldd; t.rows = r; t.cols = c; return t;
  };
  P.j[0]  = job(Wk, qkvT, 256, 256, 256, 256);
  P.j[1]  = job(Wv, qkvT + 256 * 256, 256, 256, 256, 256);
  P.j[2]  = job(Wq, qkvT + 512 * 256, 256, 256, 256, 256);
  P.j[3]  = job(Wo, woT, 256, 256, 256, 256);
  P.j[4]  = job(g1_Wr, g1rzT, 256, 512, 256, 256);
  P.j[5]  = job(g1_Ur, g1rzT + 256, 256, 512, 256, 256);
  P.j[6]  = job(g1_Wz, g1rzT + 256 * 512, 256, 512, 256, 256);
  P.j[7]  = job(g1_Uz, g1rzT + 256 * 512 + 256, 256, 512, 256, 256);
  P.j[8]  = job(g1_Wg, g1hpT, 256, 512, 256, 256);
  P.j[9]  = job(g1_Ug, g1hpT + 256, 256, 512, 256, 256);
  P.j[10] = job(W1, w1T, 512, 256, 256, 512);
  P.j[11] = job(W2, w2T, 256, 512, 512, 256);
  P.j[12] = job(g2_Wr, g2rzT, 256, 512, 256, 256);
  P.j[13] = job(g2_Ur, g2rzT + 256, 256, 512, 256, 256);
  P.j[14] = job(g2_Wz, g2rzT + 256 * 512, 256, 512, 256, 256);
  P.j[15] = job(g2_Uz, g2rzT + 256 * 512 + 256, 256, 512, 256, 256);
  P.j[16] = job(g2_Wg, g2hpT, 256, 512, 256, 256);
  P.j[17] = job(g2_Ug, g2hpT + 256, 256, 512, 256, 256);
  P.omega = omega; P.wphiT = wphiT; P.omT = omTg;
  P.bk = bk; P.bv = bv; P.bq = bq; P.bias = bias768;
  prep_kernel<<<dim3(32, 20), blk, 0, stream>>>(P);

  // ---- attention ----
  ln_kernel3<<<BN / 4, blk, 0, stream>>>(x, ln1_g, ln1_b, S0, xb);  // ln1h + xb
  gemm2<7,0,0,0><<<g3c, blkG, 0, stream>>>(S0, 256, S0, 256, qkvT, 256,
      bias768, nullptr, nullptr, sqQ, S1, S2, S3, 256, 256);        // K,V,Q + sqQ
  fkv_kernel<<<dim3(64, KSPLIT), blk, 0, stream>>>(S1, S2, omTg, kvpart);
  kvred_kernel<<<4160, blk, 0, stream>>>(kvpart, kvfin, kvbdA);
  // WoKVT[b] = Wo^T @ kvbd_b^T : M=2048 (A row wraps mod 256), Nc=512, K=256
  gemm2<0,0,0,2><<<dim3(2, 16), blkG, 0, stream>>>(woT, 256, woT, 256, kvbdA, 256,
      zero512, nullptr, nullptr, nullptr, WoKVT, nullptr, nullptr, 512, 256);
  // pq (+fused den rescale) -> db
  gemm2<10,0,0,0><<<g2c, blkG, 0, stream>>>(S3, 256, S3, 256, wphiT, 256,
      nullptr, kvfin, nullptr, sqQ, db, nullptr, nullptr, 512, 256);
  gemm2<0,0,0,1><<<g1c, blkG, 0, stream>>>(db, 512, db + 256, 512, WoKVT, 512,
      bo, nullptr, nullptr, nullptr, S3, nullptr, nullptr, 256, 512);   // y1 -> S3
  // ---- gate 1 (y=y1(S3), x=xb) ----
  gemm2<8,1,0,0><<<g2c, blkG, 0, stream>>>(S3, 256, xb, 256, g1rzT, 512,
      g1_bg, xb, nullptr, nullptr, db, db + SZB, nullptr, 256, 512);    // rx1, z1
  gemm2<9,1,0,0><<<g1c, blkG, 0, stream>>>(S3, 256, db, 256, g1hpT, 512,
      ln2_g, xb, db + SZB, ln2_b, S3, S0, nullptr, 256, 512);           // out1, ln2h
  // ---- MLP ----
  gemm2<1,0,0,0><<<g2c, blkG, 0, stream>>>(S0, 256, S0, 256, w1T, 256,
      b1, nullptr, nullptr, nullptr, db, nullptr, nullptr, 512, 256);   // hid -> db
  gemm2<1,0,0,0><<<g1c, blkG, 0, stream>>>(db, 512, db + 256, 512, w2T, 512,
      b2, nullptr, nullptr, nullptr, S1, nullptr, nullptr, 256, 512);   // y2 -> S1
  // ---- gate 2 (y=y2(S1), x=out1(S3)) ----
  gemm2<8,1,0,0><<<g2c, blkG, 0, stream>>>(S1, 256, S3, 256, g2rzT, 512,
      g2_bg, S3, nullptr, nullptr, S2, S0, nullptr, 256, 512);          // rx2, z2
  gemm2<4,1,1,0><<<g1c, blkG, 0, stream>>>(S1, 256, S2, 256, g2hpT, 512,
      nullptr, S3, S0, nullptr, outf, nullptr, nullptr, 256, 512);      // final
}